// Round 10
// baseline (405.956 us; speedup 1.0000x reference)
//
#include <hip/hip_runtime.h>
#include <hip/hip_cooperative_groups.h>
#include <math.h>

namespace cg = cooperative_groups;

#define B_   64
#define N_   512
#define C_   128
#define FS_  16
#define RES_ 511
#define CHUNK_ 64
#define HALO_  15
#define MAXR_  (CHUNK_ + HALO_)   // 79
#define RSTRIDE_ 132              // dwords per staged row (+4 pad)
#define GRID_ 512
#define BLK_  256

__device__ __forceinline__ float bf2f(unsigned short u) {
  union { unsigned int i; float f; } v;
  v.i = ((unsigned int)u) << 16;
  return v.f;
}

// dtype sniff: bf16 N(0,1) data -> ~100% of ushorts have exponent in [100,140];
// f32 data read as ushorts -> ~58% (mantissa halves random).
__device__ __forceinline__ int detect16(const unsigned short* p) {
  int sane = 0;
  for (int i = 0; i < 64; ++i) {
    int e = (p[i] >> 7) & 0xFF;
    if (e >= 100 && e <= 140) sane++;
  }
  return (sane >= 48) ? 0 : 1;   // 0 = bf16 storage, 1 = f32 storage
}

__device__ __forceinline__ float2 ld2(const void* p, int idx, int mode) {
  if (mode) return ((const float2*)p)[idx];
  ushort2 u = ((const ushort2*)p)[idx];
  return make_float2(bf2f(u.x), bf2f(u.y));
}
__device__ __forceinline__ float ld1(const void* p, int idx, int mode) {
  if (mode) return ((const float*)p)[idx];
  return bf2f(((const unsigned short*)p)[idx]);
}
__device__ __forceinline__ float4 ld4(const void* p, int idx4, int mode) {
  if (mode) return ((const float4*)p)[idx4];
  ushort4 u = ((const ushort4*)p)[idx4];
  return make_float4(bf2f(u.x), bf2f(u.y), bf2f(u.z), bf2f(u.w));
}

// wave-wide butterfly sums; identical in all 64 lanes
__device__ __forceinline__ double wred(double v) {
#pragma unroll
  for (int m = 32; m; m >>= 1) v += __shfl_xor(v, m, 64);
  return v;
}
__device__ __forceinline__ float wredf(float v) {
#pragma unroll
  for (int m = 32; m; m >>= 1) v += __shfl_xor(v, m, 64);
  return v;
}

__device__ __forceinline__ float get_epoch(const int* ep) {
  int ei = ep[0];
  if (ei >= 0 && ei <= 1000000) return (float)ei;
  union { int i; float f; } u; u.i = ei;
  return (u.f >= 0.f && u.f <= 1e6f) ? u.f : 10.f;
}

union SMem {
  struct {
    float rows[MAXR_ * RSTRIDE_];   // 41712 B
    float ads_l[MAXR_];
    float asr_l[CHUNK_];
    int   ord_l[MAXR_];
  } att;
  struct { float sl[N_]; } srt;
  struct {
    int   tab[9][N_];               // f^(2^k) jump tables, sentinel 511
    int   ol[N_];
    float wl[N_];
    float sl2[N_];
    float cl[N_];
    int   rl[N_];
    int   Pcnt;
  } chn;
};

__global__ __launch_bounds__(BLK_) void k_fused(
    const void* __restrict__ x, const void* __restrict__ w,
    const void* __restrict__ a, const int* __restrict__ ep,
    float* __restrict__ sc, float* __restrict__ asr, float* __restrict__ ads,
    int* __restrict__ order, float* __restrict__ srk,
    float* __restrict__ wrw, int* __restrict__ jmp,
    float* __restrict__ out)
{
  __shared__ SMem sm;
  __shared__ int s_modes[3];
  __shared__ float s_invtau;

  cg::grid_group grid = cg::this_grid();
  const int t = threadIdx.x, lane = t & 63, wv = t >> 6;

  if (t == 0) {
    s_modes[0] = detect16((const unsigned short*)x);
    s_modes[1] = detect16((const unsigned short*)w);
    s_modes[2] = detect16((const unsigned short*)a);
    float evv = get_epoch(ep);
    s_invtau = (float)(1.0 / (10.0 * pow(0.01, (double)evv / 100.0)));
  }
  __syncthreads();
  const int mode_x = s_modes[0], mode_w = s_modes[1], mode_a = s_modes[2];
  const float inv_tau = s_invtau;

  // ================= phase 1: per-node dots (all blocks) ==================
  // sc f64 (feeds fragile argsort); asr/ads f32 butterflies.
  {
    const float2 wv2 = ld2(w, lane, mode_w);
    const float2 sv2 = ld2(a, lane, mode_a);
    const float2 dv2 = ld2(a, 64 + lane, mode_a);
    const double nww = wred((double)wv2.x * wv2.x + (double)wv2.y * wv2.y);
    const float nrm32 = (float)sqrt(nww);
    const int gw = blockIdx.x * 4 + wv;          // 2048 waves
#pragma unroll 2
    for (int i = 0; i < 16; ++i) {               // 16 nodes per wave
      int node = gw * 16 + i;                    // < 32768
      float2 xv = ld2(x, node * 64 + lane, mode_x);
      double s  = wred((double)xv.x * wv2.x + (double)xv.y * wv2.y);
      float  da = wredf(xv.x * sv2.x + xv.y * sv2.y);
      float  dd = wredf(xv.x * dv2.x + xv.y * dv2.y);
      if (lane == 0) {
        sc[node]  = ((float)s) / nrm32;          // f32 divide, like np
        asr[node] = da;
        ads[node] = dd;
      }
    }
  }
  __threadfence();
  grid.sync();

  // ================= phase 2: stable rank sort (blocks 0..63) =============
  if (blockIdx.x < B_) {
    const int b = blockIdx.x, bN = b * N_;
    const float my0 = sc[bN + t];
    const float my1 = sc[bN + t + 256];
    sm.srt.sl[t] = my0;
    sm.srt.sl[t + 256] = my1;
    __syncthreads();
    int r0 = 0, r1 = 0;
#pragma unroll 8
    for (int k = 0; k < N_; ++k) {
      float v = sm.srt.sl[k];                    // LDS broadcast
      r0 += (int)((v > my0) || (v == my0 && k < t));
      r1 += (int)((v > my1) || (v == my1 && k < t + 256));
    }
    order[bN + r0] = t;        srk[bN + r0] = tanhf(my0);
    order[bN + r1] = t + 256;  srk[bN + r1] = tanhf(my1);
  }
  __threadfence();
  grid.sync();

  // ================= phase 3: LDS-staged attention (all blocks) ===========
  {
    const int blk = blockIdx.x;                  // b*8 + chunk
    const int b = blk >> 3;
    const int cr0 = (blk & 7) * CHUNK_;
    const int bN = b * N_;
    const int nrows = min(N_ - cr0, MAXR_);

    if (t < nrows) {
      int o = order[bN + cr0 + t];
      sm.att.ord_l[t] = o;
      sm.att.ads_l[t] = ads[bN + o];
      if (t < CHUNK_) sm.att.asr_l[t] = asr[bN + o];
    }
    __syncthreads();
    {
      const int rl0 = t >> 5, c4 = t & 31;       // 8 rows in flight, coalesced
      for (int rl = rl0; rl < nrows; rl += 8) {
        float4 v = ld4(x, (bN + sm.att.ord_l[rl]) * 32 + c4, mode_x);
        float* dst = &sm.att.rows[rl * RSTRIDE_ + c4 * 4];
        dst[0] = v.x; dst[1] = v.y; dst[2] = v.z; dst[3] = v.w;
      }
    }
    __syncthreads();

    const int j = lane & 15, cg4 = lane >> 4;
    for (int ii = 0; ii < 16; ++ii) {
      const int rloc = wv * 16 + ii;
      const int r = cr0 + rloc;
      if (r >= RES_) break;                      // wave-uniform tail trim
      const int dest = r + j;
      const bool valid = dest < N_;
      const int dl = (valid ? dest : (N_ - 1)) - cr0;

      const float* srcp = &sm.att.rows[rloc * RSTRIDE_ + cg4 * 32];
      const float* dstp = &sm.att.rows[dl   * RSTRIDE_ + cg4 * 32];
      double dacc = 0.0;
#pragma unroll
      for (int c = 0; c < 8; ++c) {
        float4 s4 = *(const float4*)(srcp + c * 4);
        float4 d4 = *(const float4*)(dstp + c * 4);
        float e0 = s4.x - d4.x, e1 = s4.y - d4.y;
        float e2 = s4.z - d4.z, e3 = s4.w - d4.w;
        float q0 = e0 * e0, q1 = e1 * e1, q2 = e2 * e2, q3 = e3 * e3;
        dacc += (double)q0; dacc += (double)q1; dacc += (double)q2; dacc += (double)q3;
      }
      dacc += __shfl_xor(dacc, 16, 64);          // reduce channel quarters
      dacc += __shfl_xor(dacc, 32, 64);

      float d32 = sqrtf((float)dacc);
      float kkj = valid ? (__expf(-0.5f * d32) - 1e-20f) : -1e-20f;
      float aaj = valid ? (sm.att.asr_l[rloc] + sm.att.ads_l[dl]) : -1e9f;
      float ttj = aaj * inv_tau;

      float mx = ttj;
#pragma unroll
      for (int m = 1; m < 16; m <<= 1) mx = fmaxf(mx, __shfl_xor(mx, m, 64));
      float eej = __expf(ttj - mx);
      float ssum = eej;
#pragma unroll
      for (int m = 1; m < 16; m <<= 1) ssum += __shfl_xor(ssum, m, 64);
      float q  = kkj * (eej * (1.0f / ssum));
      float qm = valid ? q : -1e9f;

      float wr = qm;                             // max over all j
#pragma unroll
      for (int m = 1; m < 16; m <<= 1) wr = fmaxf(wr, __shfl_xor(wr, m, 64));
      float qe = (j == 0) ? -INFINITY : qm;      // first argmax over j>=1
      float m1 = qe;
#pragma unroll
      for (int m = 1; m < 16; m <<= 1) m1 = fmaxf(m1, __shfl_xor(m1, m, 64));
      unsigned long long mask = __ballot(qe == m1);
      int bj = __builtin_ctz((unsigned)(mask & 0xFFFEu));

      if (lane == 0) {
        wrw[bN + r] = wr;
        jmp[bN + r] = bj;
      }
    }
  }
  __threadfence();
  grid.sync();

  // ================= phase 4: jump-chain pooling (blocks 0..63) ===========
  if (blockIdx.x < B_) {
    const int b = blockIdx.x, bN = b * N_;
    for (int e = t; e < N_; e += BLK_) {
      sm.chn.ol[e] = order[bN + e];
      if (e < RES_) {
        sm.chn.wl[e]  = wrw[bN + e];
        sm.chn.sl2[e] = srk[bN + e];
        sm.chn.tab[0][e] = min(e + jmp[bN + e], RES_);
      } else {
        sm.chn.tab[0][e] = RES_;
      }
    }
    if (t == 0) sm.chn.Pcnt = RES_;
    __syncthreads();
#pragma unroll
    for (int k = 1; k < 9; ++k) {
      int v0 = sm.chn.tab[k - 1][sm.chn.tab[k - 1][t]];
      int v1 = sm.chn.tab[k - 1][sm.chn.tab[k - 1][t + 256]];
      sm.chn.tab[k][t] = v0;                     // no alias with tab[k-1]
      sm.chn.tab[k][t + 256] = v1;
      __syncthreads();
    }
    for (int e = t; e < N_; e += BLK_) {
      int node = 0;
#pragma unroll
      for (int k = 0; k < 9; ++k)
        if ((e >> k) & 1) node = sm.chn.tab[k][node];
      bool valid = (node < RES_);
      sm.chn.cl[e] = valid ? sm.chn.wl[node] * sm.chn.sl2[node] : 0.0f;
      sm.chn.rl[e] = valid ? sm.chn.ol[node] : 0;
      if (!valid) atomicMin(&sm.chn.Pcnt, e);    // P = first invalid index
    }
    __syncthreads();

    if (t < C_) {
      const int P = sm.chn.Pcnt;
      float acc = 0.f;
      int i = 0;
      for (; i + 4 <= P; i += 4) {               // 4-wide load overlap
        float c0 = sm.chn.cl[i],     c1 = sm.chn.cl[i + 1];
        float c2 = sm.chn.cl[i + 2], c3 = sm.chn.cl[i + 3];
        int   r0 = sm.chn.rl[i],     r1 = sm.chn.rl[i + 1];
        int   r2 = sm.chn.rl[i + 2], r3 = sm.chn.rl[i + 3];
        float x0 = ld1(x, (bN + r0) * C_ + t, mode_x);
        float x1 = ld1(x, (bN + r1) * C_ + t, mode_x);
        float x2 = ld1(x, (bN + r2) * C_ + t, mode_x);
        float x3 = ld1(x, (bN + r3) * C_ + t, mode_x);
        acc = acc + c0 * x0;                     // exact reference order
        acc = acc + c1 * x1;
        acc = acc + c2 * x2;
        acc = acc + c3 * x3;
      }
      for (; i < P; ++i)
        acc = acc + sm.chn.cl[i] * ld1(x, (bN + sm.chn.rl[i]) * C_ + t, mode_x);
      out[b * C_ + t] = acc;
    }
  }
}

extern "C" void kernel_launch(void* const* d_in, const int* in_sizes, int n_in,
                              void* d_out, int out_size, void* d_ws, size_t ws_size,
                              hipStream_t stream) {
  const void* x = nullptr; const void* w = nullptr; const void* a = nullptr;
  const int* ep = nullptr;
  for (int i = 0; i < n_in; ++i) {
    int s = in_sizes[i];
    if      (s == B_ * N_ * C_) x  = d_in[i];
    else if (s == C_)           w  = d_in[i];
    else if (s == 2 * C_)       a  = d_in[i];
    else if (s == 1)            ep = (const int*)d_in[i];
  }
  if (!x)  x  = d_in[0];
  if (!w)  w  = d_in[2];
  if (!a)  a  = d_in[3];
  if (!ep) ep = (const int*)d_in[4];
  (void)out_size; (void)ws_size;

  float* ws = (float*)d_ws;
  const int NN = B_ * N_;              // 32768
  float* sc    = ws;                   // NN
  float* asr   = ws + NN;              // NN
  float* ads   = ws + 2 * NN;          // NN
  int*   order = (int*)(ws + 3 * NN);  // NN
  float* srk   = ws + 4 * NN;          // NN
  float* wrw   = ws + 5 * NN;          // NN
  int*   jmp   = (int*)(ws + 6 * NN);  // NN
  float* out   = (float*)d_out;

  void* args[] = { (void*)&x, (void*)&w, (void*)&a, (void*)&ep,
                   (void*)&sc, (void*)&asr, (void*)&ads,
                   (void*)&order, (void*)&srk, (void*)&wrw, (void*)&jmp,
                   (void*)&out };
  hipLaunchCooperativeKernel((const void*)k_fused, dim3(GRID_), dim3(BLK_),
                             args, 0, stream);
}

// Round 11
// 181.271 us; speedup vs baseline: 2.2395x; 2.2395x over previous
//
#include <hip/hip_runtime.h>
#include <math.h>

#define B_   64
#define N_   512
#define C_   128
#define FS_  16
#define RES_ 511
#define CHUNK_ 64
#define HALO_  15
#define MAXR_  (CHUNK_ + HALO_)   // 79
#define GSTRIDE_ 33               // dwords per 32-float channel group (+1 pad)
#define RSTRIDE_ (4 * GSTRIDE_)   // 132 dwords per staged row

__device__ __forceinline__ float bf2f(unsigned short u) {
  union { unsigned int i; float f; } v;
  v.i = ((unsigned int)u) << 16;
  return v.f;
}

// dtype sniff: bf16 N(0,1) data -> ~100% of ushorts have exponent in [100,140];
// f32 data read as ushorts -> ~58% (mantissa halves random).
__device__ __forceinline__ int detect16(const unsigned short* p) {
  int sane = 0;
  for (int i = 0; i < 64; ++i) {
    int e = (p[i] >> 7) & 0xFF;
    if (e >= 100 && e <= 140) sane++;
  }
  return (sane >= 48) ? 0 : 1;   // 0 = bf16 storage, 1 = f32 storage
}

__device__ __forceinline__ float2 ld2(const void* p, int idx, int mode) {
  if (mode) return ((const float2*)p)[idx];
  ushort2 u = ((const ushort2*)p)[idx];
  return make_float2(bf2f(u.x), bf2f(u.y));
}
__device__ __forceinline__ float ld1(const void* p, int idx, int mode) {
  if (mode) return ((const float*)p)[idx];
  return bf2f(((const unsigned short*)p)[idx]);
}
__device__ __forceinline__ float4 ld4(const void* p, int idx4, int mode) {
  if (mode) return ((const float4*)p)[idx4];
  ushort4 u = ((const ushort4*)p)[idx4];
  return make_float4(bf2f(u.x), bf2f(u.y), bf2f(u.z), bf2f(u.w));
}

// wave-wide butterfly sums; identical in all 64 lanes
__device__ __forceinline__ double wred(double v) {
#pragma unroll
  for (int m = 32; m; m >>= 1) v += __shfl_xor(v, m, 64);
  return v;
}
__device__ __forceinline__ float wredf(float v) {
#pragma unroll
  for (int m = 32; m; m >>= 1) v += __shfl_xor(v, m, 64);
  return v;
}

__device__ __forceinline__ float get_epoch(const int* ep) {
  int ei = ep[0];
  if (ei >= 0 && ei <= 1000000) return (float)ei;
  union { int i; float f; } u; u.i = ei;
  return (u.f >= 0.f && u.f <= 1e6f) ? u.f : 10.f;
}

// ---------------- Kernel A: per-node dots (one wave per node) -------------
// sc keeps f64 (feeds argsort, proven rank-flip fragile); asr/ads f32.
__global__ __launch_bounds__(256) void k_scores(
    const void* __restrict__ x, const void* __restrict__ w,
    const void* __restrict__ a,
    float* __restrict__ sc, float* __restrict__ asr, float* __restrict__ ads)
{
  __shared__ int s_modes[3];
  if (threadIdx.x == 0) {
    s_modes[0] = detect16((const unsigned short*)x);
    s_modes[1] = detect16((const unsigned short*)w);
    s_modes[2] = detect16((const unsigned short*)a);
  }
  __syncthreads();
  const int mode_x = s_modes[0], mode_w = s_modes[1], mode_a = s_modes[2];
  const int gid  = blockIdx.x * blockDim.x + threadIdx.x;
  const int wid  = gid >> 6;            // global node index, < B_*N_
  const int lane = threadIdx.x & 63;    // covers channels 2*lane, 2*lane+1

  const float2 wv2 = ld2(w, lane, mode_w);
  const float2 sv2 = ld2(a, lane, mode_a);
  const float2 dv2 = ld2(a, 64 + lane, mode_a);
  const double nww = wred((double)wv2.x * wv2.x + (double)wv2.y * wv2.y);
  const float nrm32 = (float)sqrt(nww);

  float2 xv = ld2(x, wid * 64 + lane, mode_x);
  double s  = wred((double)xv.x * wv2.x + (double)xv.y * wv2.y);
  float  da = wredf(xv.x * sv2.x + xv.y * sv2.y);
  float  dd = wredf(xv.x * dv2.x + xv.y * dv2.y);
  if (lane == 0) {
    sc[wid]  = ((float)s) / nrm32;      // f32 divide, like np
    asr[wid] = da;
    ads[wid] = dd;
  }
}

// ---------------- Kernel B: stable descending rank sort -------------------
// 512 blocks = 64 batches x 8 chunks of 64 nodes. Each thread covers
// (node, quarter); float4 LDS broadcasts; partials combined in LDS.
// rank(i) = #{k: sc[k] > sc[i]} + #{k < i: sc[k] == sc[i]}  (exact, stable)
__global__ __launch_bounds__(256) void k_sort(
    const float* __restrict__ sc, int* __restrict__ order,
    float* __restrict__ srk)
{
  __shared__ __align__(16) float sl[N_];
  __shared__ int part[4][CHUNK_];
  const int blk = blockIdx.x, b = blk >> 3, ch = blk & 7;
  const int bN = b * N_, t = threadIdx.x;
  sl[t]       = sc[bN + t];
  sl[t + 256] = sc[bN + t + 256];
  __syncthreads();
  const int n = t & 63, p = t >> 6;     // node-local, quarter
  const int g = ch * CHUNK_ + n;        // node's pre-sort index in batch
  const float my = sl[g];
  const float4* sl4 = (const float4*)sl;
  int rank = 0;
#pragma unroll 4
  for (int k4 = p * 32; k4 < p * 32 + 32; ++k4) {   // 128 compares per quarter
    float4 v = sl4[k4];                 // broadcast across the wave (free)
    int k = k4 * 4;
    rank += (int)((v.x > my) || (v.x == my && k     < g));
    rank += (int)((v.y > my) || (v.y == my && k + 1 < g));
    rank += (int)((v.z > my) || (v.z == my && k + 2 < g));
    rank += (int)((v.w > my) || (v.w == my && k + 3 < g));
  }
  part[p][n] = rank;
  __syncthreads();
  if (t < CHUNK_) {
    const int gg = ch * CHUNK_ + t;
    const int r = part[0][t] + part[1][t] + part[2][t] + part[3][t];
    order[bN + r] = gg;
    srk[bN + r]   = tanhf(sl[gg]);
  }
}

// ---------------- Kernel C: LDS-staged window attention -------------------
// 512 blocks = 64 batches x 8 chunks of 64 r. Rows staged as 4 groups of
// 32 floats, group stride 33 dwords: bank = (4*(dl+c)+cg) % 32 -> 2-way max.
__global__ __launch_bounds__(256) void k_att(
    const void* __restrict__ x, const float* __restrict__ asr,
    const float* __restrict__ ads, const int* __restrict__ order,
    const int* __restrict__ ep,
    float* __restrict__ wrw, int* __restrict__ jmp)
{
  __shared__ float rows[MAXR_ * RSTRIDE_];   // 79*132*4 = 41712 B
  __shared__ float ads_l[MAXR_];
  __shared__ float asr_l[CHUNK_];
  __shared__ int   ord_l[MAXR_];
  __shared__ int   s_mode;
  __shared__ float s_invtau;

  const int blk = blockIdx.x;           // 64*8
  const int b = blk >> 3;
  const int cr0 = (blk & 7) * CHUNK_;
  const int bN = b * N_;
  const int t = threadIdx.x;
  const int nrows = min(N_ - cr0, MAXR_);

  if (t == 0) {
    s_mode = detect16((const unsigned short*)x);
    float evv = get_epoch(ep);
    s_invtau = (float)(1.0 / (10.0 * pow(0.01, (double)evv / 100.0)));
  }
  if (t < nrows) {
    int o = order[bN + cr0 + t];
    ord_l[t] = o;
    ads_l[t] = ads[bN + o];
    if (t < CHUNK_) asr_l[t] = asr[bN + o];
  }
  __syncthreads();
  const int mode = s_mode;
  const float inv_tau = s_invtau;

  // stage rows: 8 rows in flight, 32 threads x float4 per row (coalesced);
  // swizzled store: group g4 = c4>>3 at offset g4*GSTRIDE_.
  {
    const int rl0 = t >> 5, c4 = t & 31;
    const int g4 = c4 >> 3, q = c4 & 7;
    for (int rl = rl0; rl < nrows; rl += 8) {
      float4 v = ld4(x, (bN + ord_l[rl]) * 32 + c4, mode);
      float* dst = &rows[rl * RSTRIDE_ + g4 * GSTRIDE_ + q * 4];
      dst[0] = v.x; dst[1] = v.y; dst[2] = v.z; dst[3] = v.w;
    }
  }
  __syncthreads();

  const int lane = t & 63, wv = t >> 6;
  const int j = lane & 15, cg4 = lane >> 4;

  for (int ii = 0; ii < 16; ++ii) {
    const int rloc = wv * 16 + ii;
    const int r = cr0 + rloc;
    if (r >= RES_) break;               // wave-uniform tail trim
    const int dest = r + j;
    const bool valid = dest < N_;
    const int dl = (valid ? dest : (N_ - 1)) - cr0;

    const float* srcp = &rows[rloc * RSTRIDE_ + cg4 * GSTRIDE_];
    const float* dstp = &rows[dl   * RSTRIDE_ + cg4 * GSTRIDE_];
    double dacc = 0.0;
#pragma unroll
    for (int c = 0; c < 8; ++c) {
      float4 s4 = *(const float4*)(srcp + c * 4);
      float4 d4 = *(const float4*)(dstp + c * 4);
      float e0 = s4.x - d4.x, e1 = s4.y - d4.y;   // f32 subtract, like np
      float e2 = s4.z - d4.z, e3 = s4.w - d4.w;
      float q0 = e0 * e0, q1 = e1 * e1, q2 = e2 * e2, q3 = e3 * e3;
      dacc += (double)q0; dacc += (double)q1; dacc += (double)q2; dacc += (double)q3;
    }
    dacc += __shfl_xor(dacc, 16, 64);   // reduce channel quarters
    dacc += __shfl_xor(dacc, 32, 64);

    float d32 = sqrtf((float)dacc);
    float kkj = valid ? (__expf(-0.5f * d32) - 1e-20f) : -1e-20f;
    float aaj = valid ? (asr_l[rloc] + ads_l[dl]) : -1e9f;
    float ttj = aaj * inv_tau;

    float mx = ttj;
#pragma unroll
    for (int m = 1; m < 16; m <<= 1) mx = fmaxf(mx, __shfl_xor(mx, m, 64));
    float eej = __expf(ttj - mx);
    float ssum = eej;
#pragma unroll
    for (int m = 1; m < 16; m <<= 1) ssum += __shfl_xor(ssum, m, 64);
    float q  = kkj * (eej * (1.0f / ssum));
    float qm = valid ? q : -1e9f;

    float wr = qm;                       // max over all j
#pragma unroll
    for (int m = 1; m < 16; m <<= 1) wr = fmaxf(wr, __shfl_xor(wr, m, 64));
    float qe = (j == 0) ? -INFINITY : qm;
    float m1 = qe;
#pragma unroll
    for (int m = 1; m < 16; m <<= 1) m1 = fmaxf(m1, __shfl_xor(m1, m, 64));
    unsigned long long mask = __ballot(qe == m1);
    int bj = __builtin_ctz((unsigned)(mask & 0xFFFEu));   // first argmax, j>=1

    if (lane == 0) {
      wrw[bN + r] = wr;
      jmp[bN + r] = bj;
    }
  }
}

// ---------------- Kernel D: jump-chain pooling via pointer doubling -------
__global__ __launch_bounds__(512) void k_chain(
    const void* __restrict__ x, const float* __restrict__ wrw,
    const float* __restrict__ srk, const int* __restrict__ jmp,
    const int* __restrict__ order, float* __restrict__ out)
{
  __shared__ int   tab[9][N_];   // f^(2^k) jump tables, sentinel 511
  __shared__ int   ol[N_];
  __shared__ float wl[N_];
  __shared__ float sl2[N_];
  __shared__ float cl[N_];       // coeff list in path order
  __shared__ int   rl[N_];       // row-id list
  __shared__ int   Pcnt;
  __shared__ int   s_mode;

  const int b = blockIdx.x, t = threadIdx.x;     // 512 threads
  if (t == 0) s_mode = detect16((const unsigned short*)x);

  ol[t] = order[b * N_ + t];
  if (t < RES_) {
    wl[t]  = wrw[b * N_ + t];
    sl2[t] = srk[b * N_ + t];
    tab[0][t] = min(t + jmp[b * N_ + t], RES_);
  } else {
    tab[0][t] = RES_;
  }
  if (t == 0) Pcnt = RES_;
  __syncthreads();
  const int mode_x = s_mode;
#pragma unroll
  for (int k = 1; k < 9; ++k) {
    int v = tab[k - 1][tab[k - 1][t]];
    tab[k][t] = v;
    __syncthreads();
  }
  int node = 0;
#pragma unroll
  for (int k = 0; k < 9; ++k)
    if ((t >> k) & 1) node = tab[k][node];
  bool valid = (node < RES_);
  cl[t] = valid ? wl[node] * sl2[node] : 0.0f;
  rl[t] = valid ? ol[node] : 0;
  if (!valid) atomicMin(&Pcnt, t);
  __syncthreads();

  if (t < C_) {
    const int P = Pcnt;
    float acc = 0.f;
    int i = 0;
    for (; i + 4 <= P; i += 4) {
      float c0 = cl[i],     c1 = cl[i + 1], c2 = cl[i + 2], c3 = cl[i + 3];
      int   r0 = rl[i],     r1 = rl[i + 1], r2 = rl[i + 2], r3 = rl[i + 3];
      float x0 = ld1(x, (b * N_ + r0) * C_ + t, mode_x);
      float x1 = ld1(x, (b * N_ + r1) * C_ + t, mode_x);
      float x2 = ld1(x, (b * N_ + r2) * C_ + t, mode_x);
      float x3 = ld1(x, (b * N_ + r3) * C_ + t, mode_x);
      acc = acc + c0 * x0;                       // exact reference order
      acc = acc + c1 * x1;
      acc = acc + c2 * x2;
      acc = acc + c3 * x3;
    }
    for (; i < P; ++i)
      acc = acc + cl[i] * ld1(x, (b * N_ + rl[i]) * C_ + t, mode_x);
    out[b * C_ + t] = acc;
  }
}

extern "C" void kernel_launch(void* const* d_in, const int* in_sizes, int n_in,
                              void* d_out, int out_size, void* d_ws, size_t ws_size,
                              hipStream_t stream) {
  const void* x = nullptr; const void* w = nullptr; const void* a = nullptr;
  const int* ep = nullptr;
  for (int i = 0; i < n_in; ++i) {
    int s = in_sizes[i];
    if      (s == B_ * N_ * C_) x  = d_in[i];
    else if (s == C_)           w  = d_in[i];
    else if (s == 2 * C_)       a  = d_in[i];
    else if (s == 1)            ep = (const int*)d_in[i];
  }
  if (!x)  x  = d_in[0];
  if (!w)  w  = d_in[2];
  if (!a)  a  = d_in[3];
  if (!ep) ep = (const int*)d_in[4];
  (void)out_size; (void)ws_size;

  float* ws = (float*)d_ws;
  const int NN = B_ * N_;              // 32768
  float* sc    = ws;                   // NN
  float* asr   = ws + NN;              // NN
  float* ads   = ws + 2 * NN;          // NN
  int*   order = (int*)(ws + 3 * NN);  // NN
  float* srk   = ws + 4 * NN;          // NN
  float* wrw   = ws + 5 * NN;          // NN
  int*   jmp   = (int*)(ws + 6 * NN);  // NN

  k_scores<<<NN / 4, 256, 0, stream>>>(x, w, a, sc, asr, ads);
  k_sort<<<B_ * 8, 256, 0, stream>>>(sc, order, srk);
  k_att<<<B_ * 8, 256, 0, stream>>>(x, asr, ads, order, ep, wrw, jmp);
  k_chain<<<B_, N_, 0, stream>>>(x, wrw, srk, jmp, order, (float*)d_out);
}

// Round 12
// 128.386 us; speedup vs baseline: 3.1620x; 1.4119x over previous
//
#include <hip/hip_runtime.h>
#include <math.h>

#define B_   64
#define N_   512
#define C_   128
#define FS_  16
#define RES_ 511
#define CHUNK_ 64
#define HALO_  15
#define MAXR_  (CHUNK_ + HALO_)   // 79
#define RSTRIDE_ 132              // dwords per staged row (4*33; 16B-aligned,
                                  // addr/4 mod 8 uniform in (row+j)+c -> 2-way max)

__device__ __forceinline__ float bf2f(unsigned short u) {
  union { unsigned int i; float f; } v;
  v.i = ((unsigned int)u) << 16;
  return v.f;
}

// dtype sniff: bf16 N(0,1) data -> ~100% of ushorts have exponent in [100,140];
// f32 data read as ushorts -> ~58% (mantissa halves random).
__device__ __forceinline__ int detect16(const unsigned short* p) {
  int sane = 0;
  for (int i = 0; i < 64; ++i) {
    int e = (p[i] >> 7) & 0xFF;
    if (e >= 100 && e <= 140) sane++;
  }
  return (sane >= 48) ? 0 : 1;   // 0 = bf16 storage, 1 = f32 storage
}

__device__ __forceinline__ float2 ld2(const void* p, int idx, int mode) {
  if (mode) return ((const float2*)p)[idx];
  ushort2 u = ((const ushort2*)p)[idx];
  return make_float2(bf2f(u.x), bf2f(u.y));
}
__device__ __forceinline__ float ld1(const void* p, int idx, int mode) {
  if (mode) return ((const float*)p)[idx];
  return bf2f(((const unsigned short*)p)[idx]);
}
__device__ __forceinline__ float4 ld4(const void* p, int idx4, int mode) {
  if (mode) return ((const float4*)p)[idx4];
  ushort4 u = ((const ushort4*)p)[idx4];
  return make_float4(bf2f(u.x), bf2f(u.y), bf2f(u.z), bf2f(u.w));
}

// wave-wide butterfly sums; identical in all 64 lanes
__device__ __forceinline__ double wred(double v) {
#pragma unroll
  for (int m = 32; m; m >>= 1) v += __shfl_xor(v, m, 64);
  return v;
}
__device__ __forceinline__ float wredf(float v) {
#pragma unroll
  for (int m = 32; m; m >>= 1) v += __shfl_xor(v, m, 64);
  return v;
}

__device__ __forceinline__ float get_epoch(const int* ep) {
  int ei = ep[0];
  if (ei >= 0 && ei <= 1000000) return (float)ei;
  union { int i; float f; } u; u.i = ei;
  return (u.f >= 0.f && u.f <= 1e6f) ? u.f : 10.f;
}

// ---------------- Kernel A: per-node dots (one wave per node) -------------
// sc keeps f64 (feeds argsort, proven rank-flip fragile); asr/ads f32.
__global__ __launch_bounds__(256) void k_scores(
    const void* __restrict__ x, const void* __restrict__ w,
    const void* __restrict__ a,
    float* __restrict__ sc, float* __restrict__ asr, float* __restrict__ ads)
{
  __shared__ int s_modes[3];
  if (threadIdx.x == 0) {
    s_modes[0] = detect16((const unsigned short*)x);
    s_modes[1] = detect16((const unsigned short*)w);
    s_modes[2] = detect16((const unsigned short*)a);
  }
  __syncthreads();
  const int mode_x = s_modes[0], mode_w = s_modes[1], mode_a = s_modes[2];
  const int gid  = blockIdx.x * blockDim.x + threadIdx.x;
  const int wid  = gid >> 6;            // global node index, < B_*N_
  const int lane = threadIdx.x & 63;    // covers channels 2*lane, 2*lane+1

  const float2 wv2 = ld2(w, lane, mode_w);
  const float2 sv2 = ld2(a, lane, mode_a);
  const float2 dv2 = ld2(a, 64 + lane, mode_a);
  const double nww = wred((double)wv2.x * wv2.x + (double)wv2.y * wv2.y);
  const float nrm32 = (float)sqrt(nww);

  float2 xv = ld2(x, wid * 64 + lane, mode_x);
  double s  = wred((double)xv.x * wv2.x + (double)xv.y * wv2.y);
  float  da = wredf(xv.x * sv2.x + xv.y * sv2.y);
  float  dd = wredf(xv.x * dv2.x + xv.y * dv2.y);
  if (lane == 0) {
    sc[wid]  = ((float)s) / nrm32;      // f32 divide, like np
    asr[wid] = da;
    ads[wid] = dd;
  }
}

// ---------------- Kernel B: stable descending rank sort -------------------
// 512 blocks = 64 batches x 8 chunks of 64 nodes. Each thread covers
// (node, quarter); float4 LDS broadcasts; partials combined in LDS.
// rank(i) = #{k: sc[k] > sc[i]} + #{k < i: sc[k] == sc[i]}  (exact, stable)
__global__ __launch_bounds__(256) void k_sort(
    const float* __restrict__ sc, int* __restrict__ order,
    float* __restrict__ srk)
{
  __shared__ __align__(16) float sl[N_];
  __shared__ int part[4][CHUNK_];
  const int blk = blockIdx.x, b = blk >> 3, ch = blk & 7;
  const int bN = b * N_, t = threadIdx.x;
  sl[t]       = sc[bN + t];
  sl[t + 256] = sc[bN + t + 256];
  __syncthreads();
  const int n = t & 63, p = t >> 6;     // node-local, quarter
  const int g = ch * CHUNK_ + n;        // node's pre-sort index in batch
  const float my = sl[g];
  const float4* sl4 = (const float4*)sl;
  int rank = 0;
#pragma unroll 4
  for (int k4 = p * 32; k4 < p * 32 + 32; ++k4) {   // 128 compares per quarter
    float4 v = sl4[k4];                 // broadcast across the wave (free)
    int k = k4 * 4;
    rank += (int)((v.x > my) || (v.x == my && k     < g));
    rank += (int)((v.y > my) || (v.y == my && k + 1 < g));
    rank += (int)((v.z > my) || (v.z == my && k + 2 < g));
    rank += (int)((v.w > my) || (v.w == my && k + 3 < g));
  }
  part[p][n] = rank;
  __syncthreads();
  if (t < CHUNK_) {
    const int gg = ch * CHUNK_ + t;
    const int r = part[0][t] + part[1][t] + part[2][t] + part[3][t];
    order[bN + r] = gg;
    srk[bN + r]   = tanhf(sl[gg]);
  }
}

// ---------------- Kernel C: LDS-staged window attention -------------------
// 512 blocks = 64 batches x 8 chunks of 64 r; 8 waves/block, 8 r per wave.
// R9's proven-aligned layout: store c4*4 contiguous, read cg4*32 (both
// 16B-aligned; addr/4 mod 8 uniform -> 2-way banking = free per m136).
__global__ __launch_bounds__(512) void k_att(
    const void* __restrict__ x, const float* __restrict__ asr,
    const float* __restrict__ ads, const int* __restrict__ order,
    const int* __restrict__ ep,
    float* __restrict__ wrw, int* __restrict__ jmp)
{
  __shared__ float rows[MAXR_ * RSTRIDE_];   // 79*132*4 = 41712 B
  __shared__ float ads_l[MAXR_];
  __shared__ float asr_l[CHUNK_];
  __shared__ int   ord_l[MAXR_];
  __shared__ int   s_mode;
  __shared__ float s_invtau;

  const int blk = blockIdx.x;           // 64*8
  const int b = blk >> 3;
  const int cr0 = (blk & 7) * CHUNK_;
  const int bN = b * N_;
  const int t = threadIdx.x;            // 512 threads, 8 waves
  const int nrows = min(N_ - cr0, MAXR_);

  if (t == 0) {
    s_mode = detect16((const unsigned short*)x);
    float evv = get_epoch(ep);
    s_invtau = (float)(1.0 / (10.0 * pow(0.01, (double)evv / 100.0)));
  }
  if (t < nrows) {
    int o = order[bN + cr0 + t];
    ord_l[t] = o;
    ads_l[t] = ads[bN + o];
    if (t < CHUNK_) asr_l[t] = asr[bN + o];
  }
  __syncthreads();
  const int mode = s_mode;
  const float inv_tau = s_invtau;

  // stage rows: 16 rows in flight, 32 threads x float4 per row (coalesced)
  {
    const int rl0 = t >> 5, c4 = t & 31;
    for (int rl = rl0; rl < nrows; rl += 16) {
      float4 v = ld4(x, (bN + ord_l[rl]) * 32 + c4, mode);
      float* dst = &rows[rl * RSTRIDE_ + c4 * 4];
      dst[0] = v.x; dst[1] = v.y; dst[2] = v.z; dst[3] = v.w;
    }
  }
  __syncthreads();

  const int lane = t & 63, wv = t >> 6;
  const int j = lane & 15, cg4 = lane >> 4;

  for (int ii = 0; ii < 8; ++ii) {
    const int rloc = wv * 8 + ii;       // 8 waves x 8 r = 64 r per block
    const int r = cr0 + rloc;
    if (r >= RES_) break;               // wave-uniform tail trim
    const int dest = r + j;
    const bool valid = dest < N_;
    const int dl = (valid ? dest : (N_ - 1)) - cr0;

    const float* srcp = &rows[rloc * RSTRIDE_ + cg4 * 32];
    const float* dstp = &rows[dl   * RSTRIDE_ + cg4 * 32];
    // 4 partial f64 accumulators: dep chain 8 instead of 32; value shift
    // O(1e-16) relative, decision gaps O(1e-2) -> safe.
    double p0 = 0.0, p1 = 0.0, p2 = 0.0, p3 = 0.0;
#pragma unroll
    for (int c = 0; c < 8; ++c) {
      float4 s4 = *(const float4*)(srcp + c * 4);
      float4 d4 = *(const float4*)(dstp + c * 4);
      float e0 = s4.x - d4.x, e1 = s4.y - d4.y;   // f32 subtract, like np
      float e2 = s4.z - d4.z, e3 = s4.w - d4.w;
      float q0 = e0 * e0, q1 = e1 * e1, q2 = e2 * e2, q3 = e3 * e3;
      p0 += (double)q0; p1 += (double)q1; p2 += (double)q2; p3 += (double)q3;
    }
    double dacc = (p0 + p1) + (p2 + p3);
    dacc += __shfl_xor(dacc, 16, 64);   // reduce channel quarters
    dacc += __shfl_xor(dacc, 32, 64);

    float d32 = sqrtf((float)dacc);
    float kkj = valid ? (__expf(-0.5f * d32) - 1e-20f) : -1e-20f;
    float aaj = valid ? (asr_l[rloc] + ads_l[dl]) : -1e9f;
    float ttj = aaj * inv_tau;

    float mx = ttj;
#pragma unroll
    for (int m = 1; m < 16; m <<= 1) mx = fmaxf(mx, __shfl_xor(mx, m, 64));
    float eej = __expf(ttj - mx);
    float ssum = eej;
#pragma unroll
    for (int m = 1; m < 16; m <<= 1) ssum += __shfl_xor(ssum, m, 64);
    float q  = kkj * (eej * (1.0f / ssum));
    float qm = valid ? q : -1e9f;

    float wr = qm;                       // max over all j
#pragma unroll
    for (int m = 1; m < 16; m <<= 1) wr = fmaxf(wr, __shfl_xor(wr, m, 64));
    float qe = (j == 0) ? -INFINITY : qm;
    float m1 = qe;
#pragma unroll
    for (int m = 1; m < 16; m <<= 1) m1 = fmaxf(m1, __shfl_xor(m1, m, 64));
    unsigned long long mask = __ballot(qe == m1);
    int bj = __builtin_ctz((unsigned)(mask & 0xFFFEu));   // first argmax, j>=1

    if (lane == 0) {
      wrw[bN + r] = wr;
      jmp[bN + r] = bj;
    }
  }
}

// ---------------- Kernel D: jump-chain pooling via pointer doubling -------
__global__ __launch_bounds__(512) void k_chain(
    const void* __restrict__ x, const float* __restrict__ wrw,
    const float* __restrict__ srk, const int* __restrict__ jmp,
    const int* __restrict__ order, float* __restrict__ out)
{
  __shared__ int   tab[9][N_];   // f^(2^k) jump tables, sentinel 511
  __shared__ int   ol[N_];
  __shared__ float wl[N_];
  __shared__ float sl2[N_];
  __shared__ float cl[N_];       // coeff list in path order
  __shared__ int   rl[N_];       // row-id list
  __shared__ int   Pcnt;
  __shared__ int   s_mode;

  const int b = blockIdx.x, t = threadIdx.x;     // 512 threads
  if (t == 0) s_mode = detect16((const unsigned short*)x);

  ol[t] = order[b * N_ + t];
  if (t < RES_) {
    wl[t]  = wrw[b * N_ + t];
    sl2[t] = srk[b * N_ + t];
    tab[0][t] = min(t + jmp[b * N_ + t], RES_);
  } else {
    tab[0][t] = RES_;
  }
  if (t == 0) Pcnt = RES_;
  __syncthreads();
  const int mode_x = s_mode;
#pragma unroll
  for (int k = 1; k < 9; ++k) {
    int v = tab[k - 1][tab[k - 1][t]];
    tab[k][t] = v;
    __syncthreads();
  }
  int node = 0;
#pragma unroll
  for (int k = 0; k < 9; ++k)
    if ((t >> k) & 1) node = tab[k][node];
  bool valid = (node < RES_);
  cl[t] = valid ? wl[node] * sl2[node] : 0.0f;
  rl[t] = valid ? ol[node] : 0;
  if (!valid) atomicMin(&Pcnt, t);
  __syncthreads();

  if (t < C_) {
    const int P = Pcnt;
    float acc = 0.f;
    int i = 0;
    for (; i + 4 <= P; i += 4) {
      float c0 = cl[i],     c1 = cl[i + 1], c2 = cl[i + 2], c3 = cl[i + 3];
      int   r0 = rl[i],     r1 = rl[i + 1], r2 = rl[i + 2], r3 = rl[i + 3];
      float x0 = ld1(x, (b * N_ + r0) * C_ + t, mode_x);
      float x1 = ld1(x, (b * N_ + r1) * C_ + t, mode_x);
      float x2 = ld1(x, (b * N_ + r2) * C_ + t, mode_x);
      float x3 = ld1(x, (b * N_ + r3) * C_ + t, mode_x);
      acc = acc + c0 * x0;                       // exact reference order
      acc = acc + c1 * x1;
      acc = acc + c2 * x2;
      acc = acc + c3 * x3;
    }
    for (; i < P; ++i)
      acc = acc + cl[i] * ld1(x, (b * N_ + rl[i]) * C_ + t, mode_x);
    out[b * C_ + t] = acc;
  }
}

extern "C" void kernel_launch(void* const* d_in, const int* in_sizes, int n_in,
                              void* d_out, int out_size, void* d_ws, size_t ws_size,
                              hipStream_t stream) {
  const void* x = nullptr; const void* w = nullptr; const void* a = nullptr;
  const int* ep = nullptr;
  for (int i = 0; i < n_in; ++i) {
    int s = in_sizes[i];
    if      (s == B_ * N_ * C_) x  = d_in[i];
    else if (s == C_)           w  = d_in[i];
    else if (s == 2 * C_)       a  = d_in[i];
    else if (s == 1)            ep = (const int*)d_in[i];
  }
  if (!x)  x  = d_in[0];
  if (!w)  w  = d_in[2];
  if (!a)  a  = d_in[3];
  if (!ep) ep = (const int*)d_in[4];
  (void)out_size; (void)ws_size;

  float* ws = (float*)d_ws;
  const int NN = B_ * N_;              // 32768
  float* sc    = ws;                   // NN
  float* asr   = ws + NN;              // NN
  float* ads   = ws + 2 * NN;          // NN
  int*   order = (int*)(ws + 3 * NN);  // NN
  float* srk   = ws + 4 * NN;          // NN
  float* wrw   = ws + 5 * NN;          // NN
  int*   jmp   = (int*)(ws + 6 * NN);  // NN

  k_scores<<<NN / 4, 256, 0, stream>>>(x, w, a, sc, asr, ads);
  k_sort<<<B_ * 8, 256, 0, stream>>>(sc, order, srk);
  k_att<<<B_ * 8, 512, 0, stream>>>(x, asr, ads, order, ep, wrw, jmp);
  k_chain<<<B_, N_, 0, stream>>>(x, wrw, srk, jmp, order, (float*)d_out);
}